// Round 1
// baseline (187.044 us; speedup 1.0000x reference)
//
#include <hip/hip_runtime.h>
#include <hip/hip_bf16.h>

#define BATCH 16
#define HH 384
#define WW 384
#define CINC 16
#define FOUT 32
// taps: 3x3, SAME padding, stride 1

typedef __bf16 bf16x8 __attribute__((ext_vector_type(8)));
typedef float f32x4 __attribute__((ext_vector_type(4)));

// Effective weight W[f][c][ky][kx] = ws[..] + wsilu[..]; tap = ky*3+kx.
// B-matrix for the implicit GEMM: B[k][f], k = tapsel*16 + c within a K=32 step.
// B fragment lane mapping (mfma_f32_16x16x32_bf16): col n = lane&15, k = (lane>>4)*8 + e.
__device__ inline bf16x8 compute_bfrag(const float* ws, const float* wsilu,
                                       int s, int nt, int lane) {
    int f   = (lane & 15) + 16 * nt;
    int kb  = lane >> 4;
    int tap = 2 * s + (kb >> 1);   // taps 2s, 2s+1; s=4,kb>=2 -> tap 9 (pad)
    int cb  = (kb & 1) * 8;
    bf16x8 r;
#pragma unroll
    for (int e = 0; e < 8; ++e) {
        float v = 0.f;
        if (tap < 9) {
            int idx = f * (CINC * 9) + (cb + e) * 9 + tap;
            v = ws[idx] + wsilu[idx];
        }
        r[e] = (__bf16)v;
    }
    return r;
}

// table layout: [(s*2+nt)*64 + lane] -> bf16x8 (16 B). Total 640*16 = 10240 B.
__global__ void prep_weights(const float* __restrict__ ws, const float* __restrict__ wsilu,
                             bf16x8* __restrict__ table) {
    int tid = blockIdx.x * blockDim.x + threadIdx.x;
    if (tid >= 5 * 2 * 64) return;
    int lane = tid & 63;
    int nt   = (tid >> 6) & 1;
    int s    = tid >> 7;
    table[tid] = compute_bfrag(ws, wsilu, s, nt, lane);
}

// Each block: 4 waves. Block covers (b, 16-row band, 64-px x-strip).
// Wave w: 16-px x-substrip, iterates 16 rows vertically (L1 catches 3-row halo reuse).
template <bool FROMWS>
__launch_bounds__(256)
__global__ void kanconv(const float* __restrict__ x,
                        const bf16x8* __restrict__ wtab,
                        const float* __restrict__ wsp,
                        const float* __restrict__ wsi,
                        const float* __restrict__ bias,
                        float* __restrict__ out) {
    const int id   = blockIdx.x;
    const int xb   = id % (WW / 64);
    const int yb   = (id / (WW / 64)) % (HH / 16);
    const int b    = id / ((WW / 64) * (HH / 16));
    const int lane = threadIdx.x & 63;
    const int wv   = threadIdx.x >> 6;
    const int px0  = xb * 64 + wv * 16;

    // Load (or compute) the 10 B fragments once per wave.
    bf16x8 bf[5][2];
#pragma unroll
    for (int s = 0; s < 5; ++s)
#pragma unroll
        for (int nt = 0; nt < 2; ++nt) {
            if (FROMWS)
                bf[s][nt] = wtab[(s * 2 + nt) * 64 + lane];
            else
                bf[s][nt] = compute_bfrag(wsp, wsi, s, nt, lane);
        }

    const float bias0 = bias[lane & 15];
    const float bias1 = bias[(lane & 15) + 16];

    const int m    = lane & 15;       // A row within tile
    const int kb   = lane >> 4;       // k-block
    const int tsel = kb >> 1;         // which of the 2 taps in this K-step
    const int cb   = (kb & 1) * 8;    // channel base within tap
    const int px   = px0 + m;

    for (int yi = 0; yi < 16; ++yi) {
        const int y = yb * 16 + yi;

        f32x4 acc0, acc1;
#pragma unroll
        for (int r = 0; r < 4; ++r) { acc0[r] = bias0; acc1[r] = bias1; }

#pragma unroll
        for (int s = 0; s < 5; ++s) {
            const int tap = 2 * s + tsel;
            bf16x8 a;
            bool valid = false;
            int ys = 0, xs = 0;
            if (tap < 9) {
                const int dy = tap / 3 - 1;
                const int dx = tap % 3 - 1;
                ys = y + dy;
                xs = px + dx;
                valid = ((unsigned)ys < (unsigned)HH) && ((unsigned)xs < (unsigned)WW);
            }
            if (valid) {
                const float* p = x + (((b * HH + ys) * WW + xs) * CINC + cb);
                f32x4 v0 = *(const f32x4*)(p);
                f32x4 v1 = *(const f32x4*)(p + 4);
#pragma unroll
                for (int e = 0; e < 4; ++e) { a[e] = (__bf16)v0[e]; a[e + 4] = (__bf16)v1[e]; }
            } else {
#pragma unroll
                for (int e = 0; e < 8; ++e) a[e] = (__bf16)0.f;
            }
            acc0 = __builtin_amdgcn_mfma_f32_16x16x32_bf16(a, bf[s][0], acc0, 0, 0, 0);
            acc1 = __builtin_amdgcn_mfma_f32_16x16x32_bf16(a, bf[s][1], acc1, 0, 0, 0);
        }

        // D layout: col n = lane&15, row m = (lane>>4)*4 + r
        const int orow = (b * HH + y) * WW;
#pragma unroll
        for (int r = 0; r < 4; ++r) {
            const int mm = kb * 4 + r;
            const int o  = (orow + px0 + mm) * FOUT + (lane & 15);
            out[o]      = acc0[r];
            out[o + 16] = acc1[r];
        }
    }
}

extern "C" void kernel_launch(void* const* d_in, const int* in_sizes, int n_in,
                              void* d_out, int out_size, void* d_ws, size_t ws_size,
                              hipStream_t stream) {
    const float* x     = (const float*)d_in[0];
    const float* wsp   = (const float*)d_in[1];
    const float* wsi   = (const float*)d_in[2];
    const float* bias  = (const float*)d_in[3];
    float* out         = (float*)d_out;

    const int nblk = BATCH * (HH / 16) * (WW / 64);  // 16*24*6 = 2304

    if (ws_size >= 640 * sizeof(bf16x8)) {
        bf16x8* tab = (bf16x8*)d_ws;
        prep_weights<<<3, 256, 0, stream>>>(wsp, wsi, tab);
        kanconv<true><<<nblk, 256, 0, stream>>>(x, tab, wsp, wsi, bias, out);
    } else {
        kanconv<false><<<nblk, 256, 0, stream>>>(x, nullptr, wsp, wsi, bias, out);
    }
}

// Round 2
// 116.320 us; speedup vs baseline: 1.6080x; 1.6080x over previous
//
#include <hip/hip_runtime.h>
#include <hip/hip_bf16.h>

#define BATCH 16
#define HH 384
#define WW 384
#define CINC 16
#define FOUT 32
#define BY 8            // output rows per block
#define TR 10           // LDS tile rows (BY + 2 halo)
#define TC 66           // LDS tile cols (64 + 2 halo)
#define LDSE (TR * TC * CINC)   // 10560 bf16 = 21120 B

typedef __bf16 bf16x8 __attribute__((ext_vector_type(8)));
typedef __bf16 bf16x4 __attribute__((ext_vector_type(4)));
typedef float f32x4 __attribute__((ext_vector_type(4)));

// Effective weight W[f][c][ky][kx] = ws + wsilu; tap = ky*3+kx.
// B fragment (mfma_f32_16x16x32_bf16): col n = lane&15, k = (lane>>4)*8 + e.
// K=32 packs 2 taps x 16 ch: kb 0,1 -> tap 2s ch 0-7/8-15; kb 2,3 -> tap 2s+1.
__device__ inline bf16x8 compute_bfrag(const float* ws, const float* wsilu,
                                       int s, int nt, int lane) {
    int f   = (lane & 15) + 16 * nt;
    int kb  = lane >> 4;
    int tap = 2 * s + (kb >> 1);   // s=4,kb>=2 -> tap 9 (pad)
    int cb  = (kb & 1) * 8;
    bf16x8 r;
#pragma unroll
    for (int e = 0; e < 8; ++e) {
        float v = 0.f;
        if (tap < 9) {
            int idx = f * (CINC * 9) + (cb + e) * 9 + tap;
            v = ws[idx] + wsilu[idx];
        }
        r[e] = (__bf16)v;
    }
    return r;
}

// table: [(s*2+nt)*64 + lane] -> bf16x8. 640*16 = 10240 B.
__global__ void prep_weights(const float* __restrict__ ws, const float* __restrict__ wsilu,
                             bf16x8* __restrict__ table) {
    int tid = blockIdx.x * blockDim.x + threadIdx.x;
    if (tid >= 5 * 2 * 64) return;
    int lane = tid & 63;
    int nt   = (tid >> 6) & 1;
    int s    = tid >> 7;
    table[tid] = compute_bfrag(ws, wsilu, s, nt, lane);
}

// Block: 256 thr = 4 waves. Covers (b, 8-row band, 64-px strip).
// Stage x tile (bf16) in LDS once; hot loop = 5 ds_read_b128 + 10 MFMA / row.
template <bool FROMWS>
__launch_bounds__(256)
__global__ void kanconv(const float* __restrict__ x,
                        const bf16x8* __restrict__ wtab,
                        const float* __restrict__ wsp,
                        const float* __restrict__ wsi,
                        const float* __restrict__ bias,
                        float* __restrict__ out) {
    __shared__ __bf16 lds[LDSE];

    const int nblk = BATCH * (HH / BY) * (WW / 64);   // 4608, %8==0
    int id = blockIdx.x;
    id = (id & 7) * (nblk / 8) + (id >> 3);           // XCD-aware swizzle (bijective)
    const int xb = id % (WW / 64);
    const int yb = (id / (WW / 64)) % (HH / BY);
    const int b  = id / ((WW / 64) * (HH / BY));
    const int y0 = yb * BY;
    const int x0 = xb * 64;
    const int lane = threadIdx.x & 63;
    const int wv   = threadIdx.x >> 6;

    // ---- stage input tile: rows y0-1..y0+8, cols x0-1..x0+64, all 16 ch ----
    for (int q = threadIdx.x; q < LDSE / 4; q += 256) {
        const int ch4 = q & 3;
        const int c   = (q >> 2) % TC;
        const int r   = (q >> 2) / TC;
        const int gy  = y0 - 1 + r;
        const int gx  = x0 - 1 + c;
        f32x4 v = {0.f, 0.f, 0.f, 0.f};
        if ((unsigned)gy < (unsigned)HH && (unsigned)gx < (unsigned)WW)
            v = *(const f32x4*)(x + (size_t)((b * HH + gy) * WW + gx) * CINC + ch4 * 4);
        bf16x4 h;
#pragma unroll
        for (int e = 0; e < 4; ++e) h[e] = (__bf16)v[e];
        *(bf16x4*)&lds[q * 4] = h;
    }

    // ---- weight fragments (10 per wave) ----
    bf16x8 bw[5][2];
#pragma unroll
    for (int s = 0; s < 5; ++s)
#pragma unroll
        for (int nt = 0; nt < 2; ++nt) {
            if (FROMWS) bw[s][nt] = wtab[(s * 2 + nt) * 64 + lane];
            else        bw[s][nt] = compute_bfrag(wsp, wsi, s, nt, lane);
        }

    const int m     = lane & 15;      // A row / D col
    const int kb    = lane >> 4;
    const int tsel  = kb >> 1;
    const int chalf = (kb & 1) * 8;   // channel half within tap
    const int bcol  = 1 + wv * 16 + m;

    int del[5];
#pragma unroll
    for (int s = 0; s < 5; ++s) {
        int tap = 2 * s + tsel;
        if (tap > 8) tap = 8;         // pad lane: B frag is 0, A content irrelevant
        const int dy = tap / 3 - 1;
        const int dx = tap % 3 - 1;
        del[s] = (dy * TC + dx) * CINC;
    }

    const float bias0 = bias[m];
    const float bias1 = bias[m + 16];

    __syncthreads();

    for (int yi = 0; yi < BY; ++yi) {
        const int ebase = ((yi + 1) * TC + bcol) * CINC + chalf;
        f32x4 acc0, acc1;
#pragma unroll
        for (int r = 0; r < 4; ++r) { acc0[r] = bias0; acc1[r] = bias1; }

#pragma unroll
        for (int s = 0; s < 5; ++s) {
            bf16x8 a = *(const bf16x8*)&lds[ebase + del[s]];
            acc0 = __builtin_amdgcn_mfma_f32_16x16x32_bf16(a, bw[s][0], acc0, 0, 0, 0);
            acc1 = __builtin_amdgcn_mfma_f32_16x16x32_bf16(a, bw[s][1], acc1, 0, 0, 0);
        }

        // D: col n = lane&15, row = kb*4 + r (verified layout from R0)
        const int orow = (b * HH + y0 + yi) * WW + x0 + wv * 16;
#pragma unroll
        for (int r = 0; r < 4; ++r) {
            const int o = (orow + kb * 4 + r) * FOUT + m;
            out[o]      = acc0[r];
            out[o + 16] = acc1[r];
        }
    }
}

extern "C" void kernel_launch(void* const* d_in, const int* in_sizes, int n_in,
                              void* d_out, int out_size, void* d_ws, size_t ws_size,
                              hipStream_t stream) {
    const float* x    = (const float*)d_in[0];
    const float* wsp  = (const float*)d_in[1];
    const float* wsi  = (const float*)d_in[2];
    const float* bias = (const float*)d_in[3];
    float* out        = (float*)d_out;

    const int nblk = BATCH * (HH / BY) * (WW / 64);   // 4608

    if (ws_size >= 640 * sizeof(bf16x8)) {
        bf16x8* tab = (bf16x8*)d_ws;
        prep_weights<<<3, 256, 0, stream>>>(wsp, wsi, tab);
        kanconv<true><<<nblk, 256, 0, stream>>>(x, tab, wsp, wsi, bias, out);
    } else {
        kanconv<false><<<nblk, 256, 0, stream>>>(x, nullptr, wsp, wsi, bias, out);
    }
}

// Round 3
// 102.729 us; speedup vs baseline: 1.8207x; 1.1323x over previous
//
#include <hip/hip_runtime.h>
#include <hip/hip_bf16.h>

#define BATCH 16
#define HH 384
#define WW 384
#define CINC 16
#define FOUT 32
#define BY 16           // output rows per block
#define TR 18           // LDS tile rows (BY + 2 halo)
#define TC 66           // LDS tile cols (64 + 2 halo)
#define LDSE (TR * TC * CINC)   // 19008 bf16 = 38016 B

typedef __bf16 bf16x8 __attribute__((ext_vector_type(8)));
typedef __bf16 bf16x4 __attribute__((ext_vector_type(4)));
typedef float f32x4 __attribute__((ext_vector_type(4)));

// Effective weight W[f][c][ky][kx] = ws + wsilu; tap = ky*3+kx.
// A fragment (weights) for mfma_f32_16x16x32_bf16: row i = lane&15 (= f within
// tile), k = (lane>>4)*8 + e. K=32 packs 2 taps x 16 ch:
// kb 0,1 -> tap 2s ch 0-7/8-15; kb 2,3 -> tap 2s+1.
__device__ inline bf16x8 compute_afrag(const float* ws, const float* wsilu,
                                       int s, int nt, int lane) {
    int f   = (lane & 15) + 16 * nt;
    int kb  = lane >> 4;
    int tap = 2 * s + (kb >> 1);   // s=4,kb>=2 -> tap 9 (pad -> zero)
    int cb  = (kb & 1) * 8;
    bf16x8 r;
#pragma unroll
    for (int e = 0; e < 8; ++e) {
        float v = 0.f;
        if (tap < 9) {
            int idx = f * (CINC * 9) + (cb + e) * 9 + tap;
            v = ws[idx] + wsilu[idx];
        }
        r[e] = (__bf16)v;
    }
    return r;
}

// table: [(s*2+nt)*64 + lane] -> bf16x8. 640*16 = 10240 B.
__global__ void prep_weights(const float* __restrict__ ws, const float* __restrict__ wsilu,
                             bf16x8* __restrict__ table) {
    int tid = blockIdx.x * blockDim.x + threadIdx.x;
    if (tid >= 5 * 2 * 64) return;
    int lane = tid & 63;
    int nt   = (tid >> 6) & 1;
    int s    = tid >> 7;
    table[tid] = compute_afrag(ws, wsilu, s, nt, lane);
}

// Block: 512 thr = 8 waves. Covers (b, 16-row band, 64-px strip).
// Wave wv: x-substrip (wv&3)*16, y-half (wv>>2)*8.
// Hot loop/row: 5 ds_read_b128 + 10 MFMA + 2 global_store_dwordx4.
template <bool FROMWS>
__launch_bounds__(512)
__global__ void kanconv(const float* __restrict__ x,
                        const bf16x8* __restrict__ wtab,
                        const float* __restrict__ wsp,
                        const float* __restrict__ wsi,
                        const float* __restrict__ bias,
                        float* __restrict__ out) {
    __shared__ __bf16 lds[LDSE];

    const int nblk = BATCH * (HH / BY) * (WW / 64);   // 2304, %8==0
    int id = blockIdx.x;
    id = (id & 7) * (nblk / 8) + (id >> 3);           // XCD-aware swizzle (bijective)
    const int xb = id % (WW / 64);
    const int yb = (id / (WW / 64)) % (HH / BY);
    const int b  = id / ((WW / 64) * (HH / BY));
    const int y0 = yb * BY;
    const int x0 = xb * 64;
    const int lane = threadIdx.x & 63;
    const int wv   = threadIdx.x >> 6;

    // ---- stage input tile: rows y0-1..y0+16, cols x0-1..x0+64, 16 ch, bf16 ----
    for (int q = threadIdx.x; q < LDSE / 4; q += 512) {
        const int ch4 = q & 3;
        const int c   = (q >> 2) % TC;
        const int r   = (q >> 2) / TC;
        const int gy  = y0 - 1 + r;
        const int gx  = x0 - 1 + c;
        f32x4 v = {0.f, 0.f, 0.f, 0.f};
        if ((unsigned)gy < (unsigned)HH && (unsigned)gx < (unsigned)WW)
            v = *(const f32x4*)(x + (size_t)((b * HH + gy) * WW + gx) * CINC + ch4 * 4);
        bf16x4 h;
#pragma unroll
        for (int e = 0; e < 4; ++e) h[e] = (__bf16)v[e];
        *(bf16x4*)&lds[q * 4] = h;
    }

    // ---- weight (A) fragments, 10 per wave ----
    bf16x8 aw[5][2];
#pragma unroll
    for (int s = 0; s < 5; ++s)
#pragma unroll
        for (int nt = 0; nt < 2; ++nt) {
            if (FROMWS) aw[s][nt] = wtab[(s * 2 + nt) * 64 + lane];
            else        aw[s][nt] = compute_afrag(wsp, wsi, s, nt, lane);
        }

    const int m     = lane & 15;      // B col (pixel) / D col
    const int kb    = lane >> 4;
    const int tsel  = kb >> 1;
    const int chalf = (kb & 1) * 8;   // channel half within tap
    const int sub   = (wv & 3) * 16;  // x-substrip
    const int yoff  = (wv >> 2) * 8;  // y-half
    const int bcol  = 1 + sub + m;

    int del[5];
#pragma unroll
    for (int s = 0; s < 5; ++s) {
        int tap = 2 * s + tsel;
        if (tap > 8) tap = 8;         // pad lane: A frag is 0, B content irrelevant
        const int dy = tap / 3 - 1;
        const int dx = tap % 3 - 1;
        del[s] = (dy * TC + dx) * CINC;
    }

    // bias: acc0[r] = bias[kb*4+r], acc1[r] = bias[16+kb*4+r]
    const f32x4 b0 = *(const f32x4*)(bias + kb * 4);
    const f32x4 b1 = *(const f32x4*)(bias + 16 + kb * 4);

    __syncthreads();

    for (int yi = 0; yi < 8; ++yi) {
        const int ebase = ((1 + yoff + yi) * TC + bcol) * CINC + chalf;
        f32x4 acc0 = b0, acc1 = b1;

#pragma unroll
        for (int s = 0; s < 5; ++s) {
            bf16x8 bp = *(const bf16x8*)&lds[ebase + del[s]];
            acc0 = __builtin_amdgcn_mfma_f32_16x16x32_bf16(aw[s][0], bp, acc0, 0, 0, 0);
            acc1 = __builtin_amdgcn_mfma_f32_16x16x32_bf16(aw[s][1], bp, acc1, 0, 0, 0);
        }

        // D: col = lane&15 = pixel, row = kb*4 + r = filter -> 4 consecutive ch
        const int y   = y0 + yoff + yi;
        const int pix = x0 + sub + m;
        float* po = out + (size_t)((b * HH + y) * WW + pix) * FOUT + kb * 4;
        __builtin_nontemporal_store(acc0, (f32x4*)po);
        __builtin_nontemporal_store(acc1, (f32x4*)(po + 16));
    }
}

extern "C" void kernel_launch(void* const* d_in, const int* in_sizes, int n_in,
                              void* d_out, int out_size, void* d_ws, size_t ws_size,
                              hipStream_t stream) {
    const float* x    = (const float*)d_in[0];
    const float* wsp  = (const float*)d_in[1];
    const float* wsi  = (const float*)d_in[2];
    const float* bias = (const float*)d_in[3];
    float* out        = (float*)d_out;

    const int nblk = BATCH * (HH / BY) * (WW / 64);   // 2304

    if (ws_size >= 640 * sizeof(bf16x8)) {
        bf16x8* tab = (bf16x8*)d_ws;
        prep_weights<<<3, 256, 0, stream>>>(wsp, wsi, tab);
        kanconv<true><<<nblk, 512, 0, stream>>>(x, tab, wsp, wsi, bias, out);
    } else {
        kanconv<false><<<nblk, 512, 0, stream>>>(x, nullptr, wsp, wsi, bias, out);
    }
}

// Round 4
// 97.773 us; speedup vs baseline: 1.9130x; 1.0507x over previous
//
#include <hip/hip_runtime.h>
#include <hip/hip_bf16.h>

#define BATCH 16
#define HH 384
#define WW 384
#define CINC 16
#define FOUT 32
#define BY 16           // output rows per block
#define TR 18           // LDS tile rows (BY + 2 halo)
#define TC 66           // LDS tile cols (64 + 2 halo)
#define LDSE (TR * TC * CINC)   // 19008 bf16 = 38016 B
#define NCHUNK (LDSE / 4)       // 4752 16B-chunks

typedef __bf16 bf16x8 __attribute__((ext_vector_type(8)));
typedef __bf16 bf16x4 __attribute__((ext_vector_type(4)));
typedef float f32x4 __attribute__((ext_vector_type(4)));

// Effective weight W[f][c][ky][kx] = ws + wsilu; tap = ky*3+kx.
// A fragment (weights) for mfma_f32_16x16x32_bf16: row i = lane&15 (= f within
// tile), k = (lane>>4)*8 + e. K=32 packs 2 taps x 16 ch:
// kb 0,1 -> tap 2s ch 0-7/8-15; kb 2,3 -> tap 2s+1.
__device__ inline bf16x8 compute_afrag(const float* ws, const float* wsilu,
                                       int s, int nt, int lane) {
    int f   = (lane & 15) + 16 * nt;
    int kb  = lane >> 4;
    int tap = 2 * s + (kb >> 1);   // s=4,kb>=2 -> tap 9 (pad -> zero)
    int cb  = (kb & 1) * 8;
    bf16x8 r;
#pragma unroll
    for (int e = 0; e < 8; ++e) {
        float v = 0.f;
        if (tap < 9) {
            int idx = f * (CINC * 9) + (cb + e) * 9 + tap;
            v = ws[idx] + wsilu[idx];
        }
        r[e] = (__bf16)v;
    }
    return r;
}

// table: [(s*2+nt)*64 + lane] -> bf16x8. 640*16 = 10240 B.
__global__ void prep_weights(const float* __restrict__ ws, const float* __restrict__ wsilu,
                             bf16x8* __restrict__ table) {
    int tid = blockIdx.x * blockDim.x + threadIdx.x;
    if (tid >= 5 * 2 * 64) return;
    int lane = tid & 63;
    int nt   = (tid >> 6) & 1;
    int s    = tid >> 7;
    table[tid] = compute_afrag(ws, wsilu, s, nt, lane);
}

// Block: 512 thr = 8 waves. Covers (b, 16-row band, 64-px strip).
// Staging: branchless clamped loads, 2 batches of 5 in flight per thread.
// Hot loop/row: 5 ds_read_b128 + 10 MFMA + 2 global_store_dwordx4.
template <bool FROMWS>
__launch_bounds__(512)
__global__ void kanconv(const float* __restrict__ x,
                        const bf16x8* __restrict__ wtab,
                        const float* __restrict__ wsp,
                        const float* __restrict__ wsi,
                        const float* __restrict__ bias,
                        float* __restrict__ out) {
    __shared__ __bf16 lds[LDSE];

    const int nblk = BATCH * (HH / BY) * (WW / 64);   // 2304, %8==0
    int id = blockIdx.x;
    id = (id & 7) * (nblk / 8) + (id >> 3);           // XCD-aware swizzle (bijective)
    const int xb = id % (WW / 64);
    const int yb = (id / (WW / 64)) % (HH / BY);
    const int b  = id / ((WW / 64) * (HH / BY));
    const int y0 = yb * BY;
    const int x0 = xb * 64;
    const int lane = threadIdx.x & 63;
    const int wv   = threadIdx.x >> 6;
    const int tid  = threadIdx.x;

    // ---- stage input tile: rows y0-1..y0+16, cols x0-1..x0+64, 16 ch, bf16 ----
    // 4752 chunks of 16B; 10 fixed chunks/thread, batches of 5 loads in flight.
#pragma unroll
    for (int half = 0; half < 2; ++half) {
        f32x4 vv[5];
        bool  ok[5];
#pragma unroll
        for (int it = 0; it < 5; ++it) {
            const int q    = tid + (half * 5 + it) * 512;
            const int cell = q >> 2;
            const int ch4  = q & 3;
            const int c    = cell % TC;
            const int r    = cell / TC;
            const int gy   = y0 - 1 + r;
            const int gx   = x0 - 1 + c;
            ok[it] = ((unsigned)gy < (unsigned)HH) && ((unsigned)gx < (unsigned)WW);
            const int cy = min(max(gy, 0), HH - 1);
            const int cx = min(max(gx, 0), WW - 1);
            vv[it] = *(const f32x4*)(x + ((size_t)(b * HH + cy) * WW + cx) * CINC + ch4 * 4);
        }
#pragma unroll
        for (int it = 0; it < 5; ++it) {
            const int q = tid + (half * 5 + it) * 512;
            bf16x4 h;
#pragma unroll
            for (int e = 0; e < 4; ++e)
                h[e] = ok[it] ? (__bf16)vv[it][e] : (__bf16)0.f;
            if (half == 1 && it == 4) {          // only chunk 9 can run off the end
                if (q < NCHUNK) *(bf16x4*)&lds[q * 4] = h;
            } else {
                *(bf16x4*)&lds[q * 4] = h;
            }
        }
    }

    // ---- weight (A) fragments, 10 per wave ----
    bf16x8 aw[5][2];
#pragma unroll
    for (int s = 0; s < 5; ++s)
#pragma unroll
        for (int nt = 0; nt < 2; ++nt) {
            if (FROMWS) aw[s][nt] = wtab[(s * 2 + nt) * 64 + lane];
            else        aw[s][nt] = compute_afrag(wsp, wsi, s, nt, lane);
        }

    const int m     = lane & 15;      // B col (pixel) / D col
    const int kb    = lane >> 4;
    const int tsel  = kb >> 1;
    const int chalf = (kb & 1) * 8;   // channel half within tap
    const int sub   = (wv & 3) * 16;  // x-substrip
    const int yoff  = (wv >> 2) * 8;  // y-half
    const int bcol  = 1 + sub + m;

    int del[5];
#pragma unroll
    for (int s = 0; s < 5; ++s) {
        int tap = 2 * s + tsel;
        if (tap > 8) tap = 8;         // pad lane: A frag is 0, B content irrelevant
        const int dy = tap / 3 - 1;
        const int dx = tap % 3 - 1;
        del[s] = (dy * TC + dx) * CINC;
    }

    // bias: acc0[r] = bias[kb*4+r], acc1[r] = bias[16+kb*4+r]
    const f32x4 b0 = *(const f32x4*)(bias + kb * 4);
    const f32x4 b1 = *(const f32x4*)(bias + 16 + kb * 4);

    __syncthreads();

    for (int yi = 0; yi < 8; ++yi) {
        const int ebase = ((1 + yoff + yi) * TC + bcol) * CINC + chalf;
        f32x4 acc0 = b0, acc1 = b1;

#pragma unroll
        for (int s = 0; s < 5; ++s) {
            bf16x8 bp = *(const bf16x8*)&lds[ebase + del[s]];
            acc0 = __builtin_amdgcn_mfma_f32_16x16x32_bf16(aw[s][0], bp, acc0, 0, 0, 0);
            acc1 = __builtin_amdgcn_mfma_f32_16x16x32_bf16(aw[s][1], bp, acc1, 0, 0, 0);
        }

        // D: col = lane&15 = pixel, row = kb*4 + r = filter -> 4 consecutive ch
        const int y   = y0 + yoff + yi;
        const int pix = x0 + sub + m;
        float* po = out + (size_t)((b * HH + y) * WW + pix) * FOUT + kb * 4;
        __builtin_nontemporal_store(acc0, (f32x4*)po);
        __builtin_nontemporal_store(acc1, (f32x4*)(po + 16));
    }
}

extern "C" void kernel_launch(void* const* d_in, const int* in_sizes, int n_in,
                              void* d_out, int out_size, void* d_ws, size_t ws_size,
                              hipStream_t stream) {
    const float* x    = (const float*)d_in[0];
    const float* wsp  = (const float*)d_in[1];
    const float* wsi  = (const float*)d_in[2];
    const float* bias = (const float*)d_in[3];
    float* out        = (float*)d_out;

    const int nblk = BATCH * (HH / BY) * (WW / 64);   // 2304

    if (ws_size >= 640 * sizeof(bf16x8)) {
        bf16x8* tab = (bf16x8*)d_ws;
        prep_weights<<<3, 256, 0, stream>>>(wsp, wsi, tab);
        kanconv<true><<<nblk, 512, 0, stream>>>(x, tab, wsp, wsi, bias, out);
    } else {
        kanconv<false><<<nblk, 512, 0, stream>>>(x, nullptr, wsp, wsi, bias, out);
    }
}